// Round 6
// baseline (251.601 us; speedup 1.0000x reference)
//
#include <hip/hip_runtime.h>

// Problem constants (match reference)
#define N_PTS 1048576
#define C_PT 9
#define C_LB 20
#define V1 500000
#define V8 65536

// Bucketing: 256 bins per bucket (EXACT R2 geometry — proven in-bounds/pass)
#define NB1 1954                 // ceil(V1/256)
#define NB8 256                  // V8/256
#define NBT (NB1 + NB8)          // 2210
#define KBLOCKS 256
#define PTS_PER_BLOCK (N_PTS / KBLOCKS)   // 4096
#define LB_STRIDE 21             // gcd(21,32)=1 -> spread LDS banks

// ---- bf16 helpers (manual RNE; inputs are finite) ----
__device__ __forceinline__ unsigned f2bf(float f) {
    unsigned u = __float_as_uint(f);
    u += 0x7FFFu + ((u >> 16) & 1u);
    return u >> 16;                      // low 16 bits valid
}
__device__ __forceinline__ float bf_lo(unsigned w) {   // bf16 in low half
    return __uint_as_float(w << 16);
}
__device__ __forceinline__ float bf_hi(unsigned w) {   // bf16 in high half
    return __uint_as_float(w & 0xFFFF0000u);
}

// K0: one streaming pass compresses both payloads to bf16.
// points [N,9] f32 -> ptsC [N,5] u32 (9 bf16 + pad)
// labels [N,20] f32 -> lblC [N,10] u32 (20 bf16)
// One row per thread; per-lane dword stores with stride-5/10 fully cover the
// wave's span -> L2 write-combines to full lines.
__global__ __launch_bounds__(256) void compress_kernel(const float* __restrict__ points,
                                                       const float* __restrict__ labels,
                                                       unsigned* __restrict__ ptsC,
                                                       unsigned* __restrict__ lblC)
{
    int i = blockIdx.x * 256 + threadIdx.x;      // grid 4096 * 256 == N exactly
    if (i >= N_PTS) return;

    const float* __restrict__ p = points + (size_t)i * C_PT;
    unsigned* __restrict__ pc = ptsC + (size_t)i * 5;
    pc[0] = f2bf(p[0]) | (f2bf(p[1]) << 16);
    pc[1] = f2bf(p[2]) | (f2bf(p[3]) << 16);
    pc[2] = f2bf(p[4]) | (f2bf(p[5]) << 16);
    pc[3] = f2bf(p[6]) | (f2bf(p[7]) << 16);
    pc[4] = f2bf(p[8]);

    const float4* __restrict__ l4 = reinterpret_cast<const float4*>(labels) + (size_t)i * 5;
    unsigned* __restrict__ lc = lblC + (size_t)i * 10;
    #pragma unroll
    for (int q = 0; q < 5; ++q) {
        float4 v = l4[q];
        lc[2 * q + 0] = f2bf(v.x) | (f2bf(v.y) << 16);
        lc[2 * q + 1] = f2bf(v.z) | (f2bf(v.w) << 16);
    }
}

// K1: per-block LDS histogram over all 2210 buckets -> u16 matrix row.
__global__ __launch_bounds__(1024) void count_kernel(const int* __restrict__ inv1,
                                                     const int* __restrict__ inv8,
                                                     unsigned short* __restrict__ mat)
{
    __shared__ int hist[NBT];
    for (int k = threadIdx.x; k < NBT; k += 1024) hist[k] = 0;
    __syncthreads();
    int base_i = blockIdx.x * PTS_PER_BLOCK;
    for (int t = threadIdx.x; t < PTS_PER_BLOCK; t += 1024) {
        int i = base_i + t;
        atomicAdd(&hist[inv1[i] >> 8], 1);
        atomicAdd(&hist[NB1 + (inv8[i] >> 8)], 1);
    }
    __syncthreads();
    unsigned short* row = mat + (size_t)blockIdx.x * NBT;
    for (int k = threadIdx.x; k < NBT; k += 1024) row[k] = (unsigned short)hist[k];
}

// S1: per-bucket (column) exclusive scan over the 256 blocks, in place.
__global__ __launch_bounds__(256) void colscan_kernel(unsigned short* __restrict__ mat,
                                                      int* __restrict__ total)
{
    int wave = (int)((blockIdx.x * 256 + threadIdx.x) >> 6);
    int lane = threadIdx.x & 63;
    if (wave >= NBT) return;
    int carry = 0;
    for (int c = 0; c < KBLOCKS; c += 64) {
        int b = c + lane;
        int v = (int)mat[(size_t)b * NBT + wave];
        int s = v;
        #pragma unroll
        for (int d = 1; d < 64; d <<= 1) {
            int u = __shfl_up(s, d, 64);
            if (lane >= d) s += u;
        }
        mat[(size_t)b * NBT + wave] = (unsigned short)(s - v + carry);
        carry += __shfl(s, 63, 64);
    }
    if (lane == 0) total[wave] = carry;
}

// S2: exclusive scan of bucket totals -> base (separate per scale).
__global__ __launch_bounds__(64) void basescan_kernel(const int* __restrict__ total,
                                                      int* __restrict__ base)
{
    int lane = threadIdx.x;
    int carry = 0;
    for (int c = 0; c < NB1; c += 64) {
        int k = c + lane;
        int v = (k < NB1) ? total[k] : 0;
        int s = v;
        #pragma unroll
        for (int d = 1; d < 64; d <<= 1) {
            int u = __shfl_up(s, d, 64);
            if (lane >= d) s += u;
        }
        if (k < NB1) base[k] = s - v + carry;
        carry += __shfl(s, 63, 64);
    }
    carry = 0;
    for (int c = 0; c < NB8; c += 64) {
        int k = c + lane;
        int v = total[NB1 + k];
        int s = v;
        #pragma unroll
        for (int d = 1; d < 64; d <<= 1) {
            int u = __shfl_up(s, d, 64);
            if (lane >= d) s += u;
        }
        base[NB1 + k] = s - v + carry;
        carry += __shfl(s, 63, 64);
    }
}

// K2: place each point id (packed with 8-bit in-bucket bin) into sorted arrays.
__global__ __launch_bounds__(1024) void scatter_kernel(const int* __restrict__ inv1,
                                                       const int* __restrict__ inv8,
                                                       const unsigned short* __restrict__ mat,
                                                       const int* __restrict__ base,
                                                       int* __restrict__ sorted1,
                                                       int* __restrict__ sorted8)
{
    __shared__ int off[NBT];
    __shared__ int cnt[NBT];
    const unsigned short* row = mat + (size_t)blockIdx.x * NBT;
    for (int k = threadIdx.x; k < NBT; k += 1024) {
        off[k] = base[k] + (int)row[k];
        cnt[k] = 0;
    }
    __syncthreads();
    int base_i = blockIdx.x * PTS_PER_BLOCK;
    for (int t = threadIdx.x; t < PTS_PER_BLOCK; t += 1024) {
        int i = base_i + t;
        int v1 = inv1[i];
        int k1 = v1 >> 8;
        int r1 = atomicAdd(&cnt[k1], 1);
        sorted1[off[k1] + r1] = i | ((v1 & 255) << 20);
        int v8 = inv8[i];
        int k8 = NB1 + (v8 >> 8);
        int r8 = atomicAdd(&cnt[k8], 1);
        sorted8[off[k8] + r8] = i | ((v8 & 255) << 20);
    }
}

// K3: FUSED accumulation over compressed payloads.
// Blocks [0, NB8): one scale-8 bucket each (256 bins x 20ch in LDS; 40B rows
// = 5 x uint2, 8B-aligned). Blocks [NB8, NB8+NB1): one scale-1 bucket each
// (256 bins x 9ch; 20B rows = 5 dwords). Label buckets first (8x more rows).
__global__ __launch_bounds__(1024) void accum_fused_kernel(const unsigned* __restrict__ ptsC,
                                                           const unsigned* __restrict__ lblC,
                                                           const int* __restrict__ sorted1,
                                                           const int* __restrict__ sorted8,
                                                           const int* __restrict__ base,
                                                           const int* __restrict__ total,
                                                           float* __restrict__ feat_out,
                                                           float* __restrict__ lbl_out)
{
    __shared__ float acc[256 * LB_STRIDE];
    __shared__ int cnt[256];
    if (blockIdx.x < NB8) {
        int b = blockIdx.x;
        for (int j = threadIdx.x; j < 256 * LB_STRIDE; j += 1024) acc[j] = 0.0f;
        if (threadIdx.x < 256) cnt[threadIdx.x] = 0;
        __syncthreads();
        int start = base[NB1 + b];
        int num   = total[NB1 + b];
        for (int t = threadIdx.x; t < num; t += 1024) {
            int packed = sorted8[start + t];
            int idx = packed & 0xFFFFF;
            int bin = packed >> 20;
            const unsigned* __restrict__ row = lblC + (size_t)idx * 10;
            float* a = acc + bin * LB_STRIDE;
            #pragma unroll
            for (int q = 0; q < 5; ++q) {
                uint2 w = *reinterpret_cast<const uint2*>(row + 2 * q);
                atomicAdd(&a[4 * q + 0], bf_lo(w.x));
                atomicAdd(&a[4 * q + 1], bf_hi(w.x));
                atomicAdd(&a[4 * q + 2], bf_lo(w.y));
                atomicAdd(&a[4 * q + 3], bf_hi(w.y));
            }
            atomicAdd(&cnt[bin], 1);
        }
        __syncthreads();
        size_t obase = (size_t)b * 256 * C_LB;
        for (int j = threadIdx.x; j < 256 * C_LB; j += 1024) {
            int bin = j / C_LB, c = j - bin * C_LB;
            int n = cnt[bin];
            float d = (float)(n > 0 ? n : 1);
            lbl_out[obase + j] = acc[bin * LB_STRIDE + c] / d;
        }
    } else {
        int b = blockIdx.x - NB8;
        for (int j = threadIdx.x; j < 256 * C_PT; j += 1024) acc[j] = 0.0f;
        if (threadIdx.x < 256) cnt[threadIdx.x] = 0;
        __syncthreads();
        int start = base[b];
        int num   = total[b];
        for (int t = threadIdx.x; t < num; t += 1024) {
            int packed = sorted1[start + t];
            int idx = packed & 0xFFFFF;
            int bin = packed >> 20;
            const unsigned* __restrict__ row = ptsC + (size_t)idx * 5;
            unsigned w0 = row[0], w1 = row[1], w2 = row[2], w3 = row[3], w4 = row[4];
            float* a = acc + bin * C_PT;
            atomicAdd(&a[0], bf_lo(w0)); atomicAdd(&a[1], bf_hi(w0));
            atomicAdd(&a[2], bf_lo(w1)); atomicAdd(&a[3], bf_hi(w1));
            atomicAdd(&a[4], bf_lo(w2)); atomicAdd(&a[5], bf_hi(w2));
            atomicAdd(&a[6], bf_lo(w3)); atomicAdd(&a[7], bf_hi(w3));
            atomicAdd(&a[8], bf_lo(w4));
            atomicAdd(&cnt[bin], 1);
        }
        __syncthreads();
        int vbase = b * 256;
        int nbins = min(256, V1 - vbase);
        for (int j = threadIdx.x; j < nbins * C_PT; j += 1024) {
            int bin = j / C_PT, c = j - bin * C_PT;
            int n = cnt[bin];
            float d = (float)(n > 0 ? n : 1);
            feat_out[(size_t)(vbase + bin) * C_PT + c] = acc[bin * C_PT + c] / d;
        }
    }
}

// ---------------- Fallback A: R4 proven gather kernels (uncompressed) ------
__global__ __launch_bounds__(1024) void accum8_raw_kernel(const float* __restrict__ labels,
                                                          const int* __restrict__ sorted8,
                                                          const int* __restrict__ base,
                                                          const int* __restrict__ total,
                                                          float* __restrict__ lbl_out)
{
    __shared__ float acc[256 * LB_STRIDE];
    __shared__ int cnt[256];
    for (int j = threadIdx.x; j < 256 * LB_STRIDE; j += 1024) acc[j] = 0.0f;
    if (threadIdx.x < 256) cnt[threadIdx.x] = 0;
    __syncthreads();
    int b = blockIdx.x;
    int start = base[NB1 + b];
    int num   = total[NB1 + b];
    int q = threadIdx.x & 3;
    for (int t = (int)(threadIdx.x >> 2); t < num; t += 256) {
        int packed = sorted8[start + t];
        int idx = packed & 0xFFFFF;
        int bin = packed >> 20;
        const float4* __restrict__ r4 =
            reinterpret_cast<const float4*>(labels) + (size_t)idx * 5;
        float4 v = r4[q];
        float* a = acc + bin * LB_STRIDE;
        atomicAdd(&a[q * 4 + 0], v.x);
        atomicAdd(&a[q * 4 + 1], v.y);
        atomicAdd(&a[q * 4 + 2], v.z);
        atomicAdd(&a[q * 4 + 3], v.w);
        if (q == 0) {
            float4 w = r4[4];
            atomicAdd(&a[16], w.x); atomicAdd(&a[17], w.y);
            atomicAdd(&a[18], w.z); atomicAdd(&a[19], w.w);
            atomicAdd(&cnt[bin], 1);
        }
    }
    __syncthreads();
    size_t obase = (size_t)b * 256 * C_LB;
    for (int j = threadIdx.x; j < 256 * C_LB; j += 1024) {
        int bin = j / C_LB, c = j - bin * C_LB;
        int n = cnt[bin];
        float d = (float)(n > 0 ? n : 1);
        lbl_out[obase + j] = acc[bin * LB_STRIDE + c] / d;
    }
}

__global__ __launch_bounds__(256) void accum1_raw_kernel(const float* __restrict__ points,
                                                         const int* __restrict__ sorted1,
                                                         const int* __restrict__ base,
                                                         const int* __restrict__ total,
                                                         float* __restrict__ feat_out)
{
    __shared__ float acc[256 * C_PT];
    __shared__ int cnt[256];
    for (int j = threadIdx.x; j < 256 * C_PT; j += 256) acc[j] = 0.0f;
    cnt[threadIdx.x] = 0;
    __syncthreads();
    int b = blockIdx.x;
    int start = base[b];
    int num   = total[b];
    int q = threadIdx.x & 3;
    for (int t = (int)(threadIdx.x >> 2); t < num; t += 64) {
        int packed = sorted1[start + t];
        int idx = packed & 0xFFFFF;
        int bin = packed >> 20;
        const float* __restrict__ row = points + (size_t)idx * C_PT;
        float* a = acc + bin * C_PT;
        atomicAdd(&a[q],     row[q]);
        atomicAdd(&a[q + 4], row[q + 4]);
        if (q == 0) {
            atomicAdd(&a[8], row[8]);
            atomicAdd(&cnt[bin], 1);
        }
    }
    __syncthreads();
    int vbase = b * 256;
    int nbins = min(256, V1 - vbase);
    for (int j = threadIdx.x; j < nbins * C_PT; j += 256) {
        int bin = j / C_PT, c = j - bin * C_PT;
        int n = cnt[bin];
        float d = (float)(n > 0 ? n : 1);
        feat_out[(size_t)(vbase + bin) * C_PT + c] = acc[bin * C_PT + c] / d;
    }
}

// ---------------- Fallback B: R0 atomic scatter ----------------------------
__global__ void voxel_scatter_add_kernel(const float* __restrict__ points,
                                         const int* __restrict__ inv1,
                                         const float* __restrict__ labels,
                                         const int* __restrict__ inv8,
                                         float* feat_sum, float* lbl_sum,
                                         float* cnt1, float* cnt8)
{
    int i = blockIdx.x * blockDim.x + threadIdx.x;
    if (i >= N_PTS) return;
    int v1 = inv1[i];
    int v8 = inv8[i];
    const float* p = points + (size_t)i * C_PT;
    float* f = feat_sum + (size_t)v1 * C_PT;
#pragma unroll
    for (int c = 0; c < C_PT; ++c) atomicAdd(&f[c], p[c]);
    atomicAdd(&cnt1[v1], 1.0f);
    const float* l = labels + (size_t)i * C_LB;
    float* o = lbl_sum + (size_t)v8 * C_LB;
#pragma unroll
    for (int c = 0; c < C_LB; ++c) atomicAdd(&o[c], l[c]);
    atomicAdd(&cnt8[v8], 1.0f);
}

__global__ void voxel_divide_kernel(float* out, const float* cnt1, const float* cnt8)
{
    const int totaln = V1 * C_PT + V8 * C_LB;
    for (int i = blockIdx.x * blockDim.x + threadIdx.x; i < totaln;
         i += gridDim.x * blockDim.x) {
        float c = (i < V1 * C_PT) ? cnt1[i / C_PT] : cnt8[(i - V1 * C_PT) / C_LB];
        out[i] /= fmaxf(c, 1.0f);
    }
}

extern "C" void kernel_launch(void* const* d_in, const int* in_sizes, int n_in,
                              void* d_out, int out_size, void* d_ws, size_t ws_size,
                              hipStream_t stream) {
    const float* points = (const float*)d_in[0];
    const int*   inv1   = (const int*)d_in[1];
    const float* labels = (const float*)d_in[2];
    const int*   inv8   = (const int*)d_in[3];

    float* out      = (float*)d_out;
    float* feat_out = out;                       // [V1, C_PT]
    float* lbl_out  = out + (size_t)V1 * C_PT;   // [V8, C_LB]

    // Base (R4) layout: sorted1[N] | sorted8[N] | total[NBT] | base[NBT] | mat
    const size_t base_need = ((size_t)2 * N_PTS + 2 * NBT) * sizeof(int)
                           + (size_t)KBLOCKS * NBT * sizeof(unsigned short);
    // Compressed layout adds: lblC u32[N*10] | ptsC u32[N*5] in front.
    const size_t comp_extra = (size_t)N_PTS * 15 * sizeof(unsigned);
    const int block = 256;

    if (ws_size >= base_need + comp_extra) {
        unsigned* lblC = (unsigned*)d_ws;                 // [N*10]
        unsigned* ptsC = lblC + (size_t)N_PTS * 10;       // [N*5]
        int* sorted1 = (int*)(ptsC + (size_t)N_PTS * 5);
        int* sorted8 = sorted1 + N_PTS;
        int* total   = sorted8 + N_PTS;
        int* basep   = total + NBT;
        unsigned short* mat = (unsigned short*)(basep + NBT);

        count_kernel<<<KBLOCKS, 1024, 0, stream>>>(inv1, inv8, mat);
        compress_kernel<<<N_PTS / 256, 256, 0, stream>>>(points, labels, ptsC, lblC);
        colscan_kernel<<<(NBT + 3) / 4, 256, 0, stream>>>(mat, total);
        basescan_kernel<<<1, 64, 0, stream>>>(total, basep);
        scatter_kernel<<<KBLOCKS, 1024, 0, stream>>>(inv1, inv8, mat, basep,
                                                     sorted1, sorted8);
        accum_fused_kernel<<<NB8 + NB1, 1024, 0, stream>>>(ptsC, lblC, sorted1,
                                                           sorted8, basep, total,
                                                           feat_out, lbl_out);
    } else if (ws_size >= base_need) {
        // Fallback A: proven R4 path (uncompressed gathers).
        int* sorted1 = (int*)d_ws;
        int* sorted8 = sorted1 + N_PTS;
        int* total   = sorted8 + N_PTS;
        int* basep   = total + NBT;
        unsigned short* mat = (unsigned short*)(basep + NBT);

        count_kernel<<<KBLOCKS, 1024, 0, stream>>>(inv1, inv8, mat);
        colscan_kernel<<<(NBT + 3) / 4, 256, 0, stream>>>(mat, total);
        basescan_kernel<<<1, 64, 0, stream>>>(total, basep);
        scatter_kernel<<<KBLOCKS, 1024, 0, stream>>>(inv1, inv8, mat, basep,
                                                     sorted1, sorted8);
        accum8_raw_kernel<<<NB8, 1024, 0, stream>>>(labels, sorted8, basep, total,
                                                    lbl_out);
        accum1_raw_kernel<<<NB1, 256, 0, stream>>>(points, sorted1, basep, total,
                                                   feat_out);
    } else {
        // Fallback B: naive atomic scatter (correct, slower).
        float* cnt1 = (float*)d_ws;
        float* cnt8 = cnt1 + V1;
        hipMemsetAsync(d_out, 0, (size_t)out_size * sizeof(float), stream);
        hipMemsetAsync(d_ws, 0, ((size_t)V1 + V8) * sizeof(float), stream);
        voxel_scatter_add_kernel<<<(N_PTS + block - 1) / block, block, 0, stream>>>(
            points, inv1, labels, inv8, feat_out, lbl_out, cnt1, cnt8);
        voxel_divide_kernel<<<2048, block, 0, stream>>>(out, cnt1, cnt8);
    }
}

// Round 7
// 219.735 us; speedup vs baseline: 1.1450x; 1.1450x over previous
//
#include <hip/hip_runtime.h>

// Problem constants (match reference)
#define N_PTS 1048576
#define C_PT 9
#define C_LB 20
#define V1 500000
#define V8 65536

// Bucketing: 256 bins per bucket (EXACT R2 geometry — proven in-bounds/pass)
#define NB1 1954                 // ceil(V1/256)
#define NB8 256                  // V8/256
#define NBT (NB1 + NB8)          // 2210
#define KBLOCKS 256
#define PTS_PER_BLOCK (N_PTS / KBLOCKS)   // 4096
#define LB_STRIDE 21             // gcd(21,32)=1 -> spread LDS banks

// K1: per-block LDS histogram over all 2210 buckets -> u16 matrix row.
__global__ __launch_bounds__(1024) void count_kernel(const int* __restrict__ inv1,
                                                     const int* __restrict__ inv8,
                                                     unsigned short* __restrict__ mat)
{
    __shared__ int hist[NBT];
    for (int k = threadIdx.x; k < NBT; k += 1024) hist[k] = 0;
    __syncthreads();
    int base_i = blockIdx.x * PTS_PER_BLOCK;
    for (int t = threadIdx.x; t < PTS_PER_BLOCK; t += 1024) {
        int i = base_i + t;
        atomicAdd(&hist[inv1[i] >> 8], 1);
        atomicAdd(&hist[NB1 + (inv8[i] >> 8)], 1);
    }
    __syncthreads();
    unsigned short* row = mat + (size_t)blockIdx.x * NBT;
    for (int k = threadIdx.x; k < NBT; k += 1024) row[k] = (unsigned short)hist[k];
}

// S1: per-bucket (column) exclusive scan over the 256 blocks, in place.
__global__ __launch_bounds__(256) void colscan_kernel(unsigned short* __restrict__ mat,
                                                      int* __restrict__ total)
{
    int wave = (int)((blockIdx.x * 256 + threadIdx.x) >> 6);
    int lane = threadIdx.x & 63;
    if (wave >= NBT) return;
    int carry = 0;
    for (int c = 0; c < KBLOCKS; c += 64) {
        int b = c + lane;
        int v = (int)mat[(size_t)b * NBT + wave];
        int s = v;
        #pragma unroll
        for (int d = 1; d < 64; d <<= 1) {
            int u = __shfl_up(s, d, 64);
            if (lane >= d) s += u;
        }
        mat[(size_t)b * NBT + wave] = (unsigned short)(s - v + carry);
        carry += __shfl(s, 63, 64);
    }
    if (lane == 0) total[wave] = carry;
}

// S2: exclusive scan of bucket totals -> base (separate per scale).
__global__ __launch_bounds__(64) void basescan_kernel(const int* __restrict__ total,
                                                      int* __restrict__ base)
{
    int lane = threadIdx.x;
    int carry = 0;
    for (int c = 0; c < NB1; c += 64) {
        int k = c + lane;
        int v = (k < NB1) ? total[k] : 0;
        int s = v;
        #pragma unroll
        for (int d = 1; d < 64; d <<= 1) {
            int u = __shfl_up(s, d, 64);
            if (lane >= d) s += u;
        }
        if (k < NB1) base[k] = s - v + carry;
        carry += __shfl(s, 63, 64);
    }
    carry = 0;
    for (int c = 0; c < NB8; c += 64) {
        int k = c + lane;
        int v = total[NB1 + k];
        int s = v;
        #pragma unroll
        for (int d = 1; d < 64; d <<= 1) {
            int u = __shfl_up(s, d, 64);
            if (lane >= d) s += u;
        }
        base[NB1 + k] = s - v + carry;
        carry += __shfl(s, 63, 64);
    }
}

// K2: place each point id (packed with 8-bit in-bucket bin) into sorted arrays.
__global__ __launch_bounds__(1024) void scatter_kernel(const int* __restrict__ inv1,
                                                       const int* __restrict__ inv8,
                                                       const unsigned short* __restrict__ mat,
                                                       const int* __restrict__ base,
                                                       int* __restrict__ sorted1,
                                                       int* __restrict__ sorted8)
{
    __shared__ int off[NBT];
    __shared__ int cnt[NBT];
    const unsigned short* row = mat + (size_t)blockIdx.x * NBT;
    for (int k = threadIdx.x; k < NBT; k += 1024) {
        off[k] = base[k] + (int)row[k];
        cnt[k] = 0;
    }
    __syncthreads();
    int base_i = blockIdx.x * PTS_PER_BLOCK;
    for (int t = threadIdx.x; t < PTS_PER_BLOCK; t += 1024) {
        int i = base_i + t;
        int v1 = inv1[i];
        int k1 = v1 >> 8;
        int r1 = atomicAdd(&cnt[k1], 1);
        sorted1[off[k1] + r1] = i | ((v1 & 255) << 20);
        int v8 = inv8[i];
        int k8 = NB1 + (v8 >> 8);
        int r8 = atomicAdd(&cnt[k8], 1);
        sorted8[off[k8] + r8] = i | ((v8 & 255) << 20);
    }
}

// K3: FUSED accumulation, 128-thread blocks, BATCH-4 register gathering.
// Blocks [0, NB8): label buckets (4096 rows each, 32 rows/thread).
// Blocks [NB8, NB8+NB1): point buckets (~537 rows each, ~4 rows/thread).
// Each thread issues ALL payload loads for 4 rows (80 floats labels / 36
// points -> ~8 independent cache lines in flight per lane) BEFORE the LDS
// atomic phase, multiplying per-CU line concurrency ~4-8x vs R2/R4/R5.
__global__ __launch_bounds__(128) void accum_fused_kernel(const float* __restrict__ points,
                                                          const float* __restrict__ labels,
                                                          const int* __restrict__ sorted1,
                                                          const int* __restrict__ sorted8,
                                                          const int* __restrict__ base,
                                                          const int* __restrict__ total,
                                                          float* __restrict__ feat_out,
                                                          float* __restrict__ lbl_out)
{
    __shared__ float acc[256 * LB_STRIDE];   // labels use 256*21; points use 256*9
    __shared__ int cnt[256];

    if (blockIdx.x < NB8) {
        // ---- labels bucket ----
        int b = blockIdx.x;
        for (int j = threadIdx.x; j < 256 * LB_STRIDE; j += 128) acc[j] = 0.0f;
        for (int j = threadIdx.x; j < 256; j += 128) cnt[j] = 0;
        __syncthreads();
        int start = base[NB1 + b];
        int num   = total[NB1 + b];
        for (int t0 = threadIdx.x; t0 < num; t0 += 512) {
            int pk[4];
            bool ok[4];
            #pragma unroll
            for (int j = 0; j < 4; ++j) {
                int t = t0 + j * 128;
                ok[j] = (t < num);
                pk[j] = ok[j] ? sorted8[start + t] : 0;
            }
            float v[4][C_LB];
            #pragma unroll
            for (int j = 0; j < 4; ++j) {
                const float* __restrict__ r = labels + (size_t)(pk[j] & 0xFFFFF) * C_LB;
                #pragma unroll
                for (int c = 0; c < C_LB; ++c) v[j][c] = r[c];
            }
            #pragma unroll
            for (int j = 0; j < 4; ++j) {
                if (!ok[j]) break;           // only tail batch diverges
                int bin = pk[j] >> 20;
                float* a = acc + bin * LB_STRIDE;
                #pragma unroll
                for (int c = 0; c < C_LB; ++c) atomicAdd(&a[c], v[j][c]);
                atomicAdd(&cnt[bin], 1);
            }
        }
        __syncthreads();
        size_t obase = (size_t)b * 256 * C_LB;
        for (int j = threadIdx.x; j < 256 * C_LB; j += 128) {
            int bin = j / C_LB, c = j - bin * C_LB;
            int n = cnt[bin];
            float d = (float)(n > 0 ? n : 1);
            lbl_out[obase + j] = acc[bin * LB_STRIDE + c] / d;
        }
    } else {
        // ---- points bucket ----
        int b = blockIdx.x - NB8;
        for (int j = threadIdx.x; j < 256 * C_PT; j += 128) acc[j] = 0.0f;
        for (int j = threadIdx.x; j < 256; j += 128) cnt[j] = 0;
        __syncthreads();
        int start = base[b];
        int num   = total[b];
        for (int t0 = threadIdx.x; t0 < num; t0 += 512) {
            int pk[4];
            bool ok[4];
            #pragma unroll
            for (int j = 0; j < 4; ++j) {
                int t = t0 + j * 128;
                ok[j] = (t < num);
                pk[j] = ok[j] ? sorted1[start + t] : 0;
            }
            float v[4][C_PT];
            #pragma unroll
            for (int j = 0; j < 4; ++j) {
                const float* __restrict__ r = points + (size_t)(pk[j] & 0xFFFFF) * C_PT;
                #pragma unroll
                for (int c = 0; c < C_PT; ++c) v[j][c] = r[c];
            }
            #pragma unroll
            for (int j = 0; j < 4; ++j) {
                if (!ok[j]) break;
                int bin = pk[j] >> 20;
                float* a = acc + bin * C_PT;
                #pragma unroll
                for (int c = 0; c < C_PT; ++c) atomicAdd(&a[c], v[j][c]);
                atomicAdd(&cnt[bin], 1);
            }
        }
        __syncthreads();
        int vbase = b * 256;
        int nbins = min(256, V1 - vbase);
        for (int j = threadIdx.x; j < nbins * C_PT; j += 128) {
            int bin = j / C_PT, c = j - bin * C_PT;
            int n = cnt[bin];
            float d = (float)(n > 0 ? n : 1);
            feat_out[(size_t)(vbase + bin) * C_PT + c] = acc[bin * C_PT + c] / d;
        }
    }
}

// ---------------- Fallback: R0 atomic scatter (ws tiny) --------------------
__global__ void voxel_scatter_add_kernel(const float* __restrict__ points,
                                         const int* __restrict__ inv1,
                                         const float* __restrict__ labels,
                                         const int* __restrict__ inv8,
                                         float* feat_sum, float* lbl_sum,
                                         float* cnt1, float* cnt8)
{
    int i = blockIdx.x * blockDim.x + threadIdx.x;
    if (i >= N_PTS) return;
    int v1 = inv1[i];
    int v8 = inv8[i];
    const float* p = points + (size_t)i * C_PT;
    float* f = feat_sum + (size_t)v1 * C_PT;
#pragma unroll
    for (int c = 0; c < C_PT; ++c) atomicAdd(&f[c], p[c]);
    atomicAdd(&cnt1[v1], 1.0f);
    const float* l = labels + (size_t)i * C_LB;
    float* o = lbl_sum + (size_t)v8 * C_LB;
#pragma unroll
    for (int c = 0; c < C_LB; ++c) atomicAdd(&o[c], l[c]);
    atomicAdd(&cnt8[v8], 1.0f);
}

__global__ void voxel_divide_kernel(float* out, const float* cnt1, const float* cnt8)
{
    const int totaln = V1 * C_PT + V8 * C_LB;
    for (int i = blockIdx.x * blockDim.x + threadIdx.x; i < totaln;
         i += gridDim.x * blockDim.x) {
        float c = (i < V1 * C_PT) ? cnt1[i / C_PT] : cnt8[(i - V1 * C_PT) / C_LB];
        out[i] /= fmaxf(c, 1.0f);
    }
}

extern "C" void kernel_launch(void* const* d_in, const int* in_sizes, int n_in,
                              void* d_out, int out_size, void* d_ws, size_t ws_size,
                              hipStream_t stream) {
    const float* points = (const float*)d_in[0];
    const int*   inv1   = (const int*)d_in[1];
    const float* labels = (const float*)d_in[2];
    const int*   inv8   = (const int*)d_in[3];

    float* out      = (float*)d_out;
    float* feat_out = out;                       // [V1, C_PT]
    float* lbl_out  = out + (size_t)V1 * C_PT;   // [V8, C_LB]

    // ws layout (EXACT R2): sorted1[N] | sorted8[N] | total[NBT] | base[NBT] | mat u16[256][NBT]
    const size_t need = ((size_t)2 * N_PTS + 2 * NBT) * sizeof(int)
                      + (size_t)KBLOCKS * NBT * sizeof(unsigned short);
    if (ws_size >= need) {
        int* sorted1 = (int*)d_ws;
        int* sorted8 = sorted1 + N_PTS;
        int* total   = sorted8 + N_PTS;
        int* basep   = total + NBT;
        unsigned short* mat = (unsigned short*)(basep + NBT);

        count_kernel<<<KBLOCKS, 1024, 0, stream>>>(inv1, inv8, mat);
        colscan_kernel<<<(NBT + 3) / 4, 256, 0, stream>>>(mat, total);
        basescan_kernel<<<1, 64, 0, stream>>>(total, basep);
        scatter_kernel<<<KBLOCKS, 1024, 0, stream>>>(inv1, inv8, mat, basep,
                                                     sorted1, sorted8);
        accum_fused_kernel<<<NB8 + NB1, 128, 0, stream>>>(points, labels, sorted1,
                                                          sorted8, basep, total,
                                                          feat_out, lbl_out);
    } else {
        // Fallback: naive atomic scatter (correct, slower).
        float* cnt1 = (float*)d_ws;
        float* cnt8 = cnt1 + V1;
        hipMemsetAsync(d_out, 0, (size_t)out_size * sizeof(float), stream);
        hipMemsetAsync(d_ws, 0, ((size_t)V1 + V8) * sizeof(float), stream);
        const int block = 256;
        voxel_scatter_add_kernel<<<(N_PTS + block - 1) / block, block, 0, stream>>>(
            points, inv1, labels, inv8, feat_out, lbl_out, cnt1, cnt8);
        voxel_divide_kernel<<<2048, block, 0, stream>>>(out, cnt1, cnt8);
    }
}